// Round 10
// baseline (186.972 us; speedup 1.0000x reference)
//
#include <hip/hip_runtime.h>

typedef __attribute__((ext_vector_type(8))) short bf16x8;
typedef __attribute__((ext_vector_type(4))) float f32x4;
typedef __attribute__((ext_vector_type(4))) _Float16 f16x4;

#define NPTS   40000
#define MOUT   40000
#define EDG    500000
#define FIN    32
#define COUT   64
#define KP     15
#define KFDIM  (KP * FIN)          // 480
#define ASTRIDE 488                // LDS row stride (bf16): 976B rows, b128-conflict-free
#define EXTENT 0.6f

#define FEAT_BLKS  (NPTS * FIN / 1024)            // 1250
#define PTS_BLKS   ((NPTS + 255) / 256)           // 157
#define ROW_BLKS   ((EDG + 255) / 256)            // 1954
#define PRE_BLKS   (FEAT_BLKS + PTS_BLKS + ROW_BLKS)

__device__ __forceinline__ short f2bf(float x) {
    union { float f; unsigned u; } v; v.f = x;
    unsigned r = (v.u + 0x7fffu + ((v.u >> 16) & 1u)) >> 16;
    return (short)r;
}

// ============================================================================
// Preprocess (one launch, branch by block range):
//   [0, 1250)        features f32 -> f16
//   [1250, 1407)     points -> float4 pad
//   [1407, 3361)     CSR row starts via scatter (disjoint ranges, no atomics)
// ============================================================================
__global__ __launch_bounds__(256) void preprocess_all(
    const float* __restrict__ features, _Float16* __restrict__ feat_h,
    const float* __restrict__ pts, float4* __restrict__ p4,
    const int* __restrict__ seg_ids, int* __restrict__ row_start)
{
    const int bid = blockIdx.x;
    if (bid < FEAT_BLKS) {
        const int i = (bid * 256 + threadIdx.x) * 4;
        const float4 v = *(const float4*)(features + i);
        feat_h[i + 0] = (_Float16)v.x;
        feat_h[i + 1] = (_Float16)v.y;
        feat_h[i + 2] = (_Float16)v.z;
        feat_h[i + 3] = (_Float16)v.w;
    } else if (bid < FEAT_BLKS + PTS_BLKS) {
        const int i = (bid - FEAT_BLKS) * 256 + threadIdx.x;
        if (i < NPTS) {
            const float* p = pts + 3 * i;
            p4[i] = make_float4(p[0], p[1], p[2], 0.f);
        }
    } else {
        const int e = (bid - FEAT_BLKS - PTS_BLKS) * 256 + threadIdx.x;
        if (e >= EDG) return;
        const int cur  = seg_ids[e];
        const int prev = (e == 0) ? -1 : seg_ids[e - 1];
        for (int m = prev + 1; m <= cur; ++m) row_start[m] = e;
        if (e == EDG - 1)
            for (int m = cur + 1; m <= MOUT; ++m) row_start[m] = EDG;
    }
}

// ============================================================================
// Fused main kernel. Block = 16 segments.
// Phase 1 (per wave, 4 segments serially): K=16 f16 MFMA aggregation
//   A[kpoint][edge]: kpoint=lane&15, edge=quad*4+j ; B[edge][f]: f=lane&15
//   D: col=f, row=quad*4+r (=kpoint) -> 8 ds_write_b16 into LDS agg row.
// Phase 2 (per wave, 16 cols): 15x mfma 16x16x32_bf16, A=ds_read_b128 from
//   LDS (488-stride, conflict-free), B=prefetched k_values fragments.
// B prefetch BEFORE phase 1 + cap 128 is the known no-spill combo (R4 ✓);
// in-loop B under a tight cap spilled (R5 ✗). (256,4): cap 128.
// ============================================================================
__global__ __launch_bounds__(256, 4) void kpconv_fused_mfma(
    const float4* __restrict__ points4,
    const _Float16* __restrict__ feat_h,
    const float* __restrict__ output_points,
    const int*   __restrict__ nbr_idx,
    const int*   __restrict__ row_start,
    const float* __restrict__ k_points,
    const float* __restrict__ k_values,
    float* __restrict__ out)
{
    __shared__ __align__(16) unsigned short agg[16 * ASTRIDE];  // 15616 B

    const int tid  = threadIdx.x;
    const int wave = tid >> 6;
    const int lane = tid & 63;
    const int quad = lane >> 4;
    const int l16  = lane & 15;
    const int m0   = blockIdx.x * 16;

    // ---- B-fragment prefetch (held across phase 1; R4-proven) ----
    bf16x8 bfr[15];
    const int bcol = wave * 16 + l16;
    #pragma unroll
    for (int s = 0; s < 15; ++s) {
        #pragma unroll
        for (int j = 0; j < 8; ++j)
            bfr[s][j] = f2bf(k_values[(32 * s + quad * 8 + j) * COUT + bcol]);
    }

    // ---- Phase 1: MFMA aggregation, 4 segments per wave ----
    const int myk = l16 < KP ? l16 : 0;
    const float kpx = k_points[myk * 3 + 0];
    const float kpy = k_points[myk * 3 + 1];
    const float kpz = k_points[myk * 3 + 2];
    const float inv_ext = 1.f / EXTENT;

    for (int s = 0; s < 4; ++s) {
        const int li = wave * 4 + s;          // local segment 0..15
        const int m  = m0 + li;
        const int e0 = row_start[m], e1 = row_start[m + 1];

        const float ox = output_points[m * 3 + 0];
        const float oy = output_points[m * 3 + 1];
        const float oz = output_points[m * 3 + 2];

        f32x4 c_lo = {0.f, 0.f, 0.f, 0.f};
        f32x4 c_hi = {0.f, 0.f, 0.f, 0.f};

        for (int es = e0; es < e1; es += 16) {
            const int last = e1 - 1;
            const int ebase = es + quad * 4;

            int nb[4];
            #pragma unroll
            for (int j = 0; j < 4; ++j) {
                const int e = ebase + j;
                nb[j] = nbr_idx[e < e1 ? e : last];   // clamp; w=0 for tails
            }

            f16x4 afrag, blo, bhi;
            #pragma unroll
            for (int j = 0; j < 4; ++j) {
                const float4 p = points4[nb[j]];
                const float rx = p.x - ox;
                const float ry = p.y - oy;
                const float rz = p.z - oz;
                const float dx = rx - kpx, dy = ry - kpy, dz = rz - kpz;
                const float d2 = dx * dx + dy * dy + dz * dz;
                float w = 1.f - sqrtf(d2) * inv_ext;
                w = w > 0.f ? w : 0.f;
                if (l16 >= KP || ebase + j >= e1) w = 0.f;
                afrag[j] = (_Float16)w;
            }

            #pragma unroll
            for (int j = 0; j < 4; ++j) {
                const _Float16* fp = feat_h + nb[j] * FIN + l16;
                blo[j] = fp[0];
                bhi[j] = fp[16];
            }

            c_lo = __builtin_amdgcn_mfma_f32_16x16x16f16(afrag, blo, c_lo, 0, 0, 0);
            c_hi = __builtin_amdgcn_mfma_f32_16x16x16f16(afrag, bhi, c_hi, 0, 0, 0);
        }

        // D layout: col=f (=l16), row=quad*4+r (=kpoint); k=15 row unused
        unsigned short* dst = agg + li * ASTRIDE;
        #pragma unroll
        for (int r = 0; r < 4; ++r) {
            const int krow = quad * 4 + r;
            if (krow < KP) {
                dst[krow * FIN + l16]      = (unsigned short)f2bf(c_lo[r]);
                dst[krow * FIN + 16 + l16] = (unsigned short)f2bf(c_hi[r]);
            }
        }
    }

    __syncthreads();

    // ---- Phase 2: C[16x16] per wave via 15 MFMAs over K=480 ----
    f32x4 c = {0.f, 0.f, 0.f, 0.f};
    #pragma unroll
    for (int s = 0; s < 15; ++s) {
        const bf16x8 af = *(const bf16x8*)&agg[l16 * ASTRIDE + 32 * s + quad * 8];
        c = __builtin_amdgcn_mfma_f32_16x16x32_bf16(af, bfr[s], c, 0, 0, 0);
    }

    // C/D layout: col = lane&15, row = quad*4 + reg
    #pragma unroll
    for (int r = 0; r < 4; ++r) {
        const int row = quad * 4 + r;
        out[(m0 + row) * COUT + bcol] = c[r];
    }
}

// ============================================================================
// Fallback (small ws): R7-style K=32 MFMA agg with in-kernel binary search,
// then gemm — needs only 38.4 MB.
// ============================================================================
__global__ __launch_bounds__(256, 4) void kpconv_agg_mfma(
    const float* __restrict__ points,
    const float* __restrict__ features,
    const float* __restrict__ output_points,
    const int*   __restrict__ nbr_idx,
    const int*   __restrict__ seg_ids,
    const float* __restrict__ k_points,
    unsigned short* __restrict__ agg_g)
{
    __shared__ int seg_start[5];

    const int tid  = threadIdx.x;
    const int m0   = blockIdx.x * 4;

    if (tid <= 4) {
        const int target = m0 + tid;
        int lo = 0, hi = EDG;
        while (lo < hi) {
            int mid = (lo + hi) >> 1;
            if (seg_ids[mid] < target) lo = mid + 1; else hi = mid;
        }
        seg_start[tid] = lo;
    }
    __syncthreads();

    const int wave = tid >> 6;
    const int lane = tid & 63;
    const int quad = lane >> 4;
    const int l16  = lane & 15;

    const int m = m0 + wave;
    const float ox = output_points[m * 3 + 0];
    const float oy = output_points[m * 3 + 1];
    const float oz = output_points[m * 3 + 2];

    const int myk = l16 < KP ? l16 : 0;
    const float kpx = k_points[myk * 3 + 0];
    const float kpy = k_points[myk * 3 + 1];
    const float kpz = k_points[myk * 3 + 2];
    const float inv_ext = 1.f / EXTENT;

    const int e0 = seg_start[wave], e1 = seg_start[wave + 1];

    f32x4 c_lo = {0.f, 0.f, 0.f, 0.f};
    f32x4 c_hi = {0.f, 0.f, 0.f, 0.f};

    for (int es = e0; es < e1; es += 32) {
        const int last = e1 - 1;
        const int ebase = es + quad * 8;

        int nb[8];
        #pragma unroll
        for (int j = 0; j < 8; ++j) {
            const int e = ebase + j;
            nb[j] = nbr_idx[e < e1 ? e : last];
        }

        bf16x8 afrag, blo, bhi;
        #pragma unroll
        for (int j = 0; j < 8; ++j) {
            const float* pp = points + nb[j] * 3;
            const float rx = pp[0] - ox;
            const float ry = pp[1] - oy;
            const float rz = pp[2] - oz;
            const float dx = rx - kpx, dy = ry - kpy, dz = rz - kpz;
            const float d2 = dx * dx + dy * dy + dz * dz;
            float w = 1.f - sqrtf(d2) * inv_ext;
            w = w > 0.f ? w : 0.f;
            if (l16 >= KP || ebase + j >= e1) w = 0.f;
            afrag[j] = f2bf(w);
        }

        #pragma unroll
        for (int j = 0; j < 8; ++j) {
            const float* fp = features + nb[j] * FIN + l16;
            blo[j] = f2bf(fp[0]);
            bhi[j] = f2bf(fp[16]);
        }

        c_lo = __builtin_amdgcn_mfma_f32_16x16x32_bf16(afrag, blo, c_lo, 0, 0, 0);
        c_hi = __builtin_amdgcn_mfma_f32_16x16x32_bf16(afrag, bhi, c_hi, 0, 0, 0);
    }

    unsigned short* dst = agg_g + (size_t)m * KFDIM;
    #pragma unroll
    for (int r = 0; r < 4; ++r) {
        const int krow = quad * 4 + r;
        if (krow < KP) {
            dst[krow * FIN + l16]      = (unsigned short)f2bf(c_lo[r]);
            dst[krow * FIN + 16 + l16] = (unsigned short)f2bf(c_hi[r]);
        }
    }
}

__global__ __launch_bounds__(256, 4) void kpconv_gemm(
    const unsigned short* __restrict__ agg_g,
    const float* __restrict__ k_values,
    float* __restrict__ out)
{
    const int tid  = threadIdx.x;
    const int wave = tid >> 6;
    const int lane = tid & 63;
    const int quad = lane >> 4;
    const int l16  = lane & 15;
    const int m0   = blockIdx.x * 32;
    const int bcol = wave * 16 + l16;

    bf16x8 bfr[15];
    #pragma unroll
    for (int s = 0; s < 15; ++s) {
        #pragma unroll
        for (int j = 0; j < 8; ++j)
            bfr[s][j] = f2bf(k_values[(32 * s + quad * 8 + j) * COUT + bcol]);
    }

    const unsigned short* arow0 = agg_g + (size_t)(m0 + l16) * KFDIM + quad * 8;
    const unsigned short* arow1 = arow0 + 16 * KFDIM;

    f32x4 c0 = {0.f, 0.f, 0.f, 0.f};
    f32x4 c1 = {0.f, 0.f, 0.f, 0.f};
    #pragma unroll
    for (int s = 0; s < 15; ++s) {
        const bf16x8 a0 = *(const bf16x8*)(arow0 + 32 * s);
        const bf16x8 a1 = *(const bf16x8*)(arow1 + 32 * s);
        c0 = __builtin_amdgcn_mfma_f32_16x16x32_bf16(a0, bfr[s], c0, 0, 0, 0);
        c1 = __builtin_amdgcn_mfma_f32_16x16x32_bf16(a1, bfr[s], c1, 0, 0, 0);
    }

    #pragma unroll
    for (int r = 0; r < 4; ++r) {
        out[(m0 + quad * 4 + r) * COUT + bcol]      = c0[r];
        out[(m0 + 16 + quad * 4 + r) * COUT + bcol] = c1[r];
    }
}

extern "C" void kernel_launch(void* const* d_in, const int* in_sizes, int n_in,
                              void* d_out, int out_size, void* d_ws, size_t ws_size,
                              hipStream_t stream) {
    const float* points        = (const float*)d_in[0];
    const float* features      = (const float*)d_in[1];
    const float* output_points = (const float*)d_in[2];
    const int*   nbr_idx       = (const int*)d_in[3];
    const int*   seg_ids       = (const int*)d_in[4];
    const float* k_points      = (const float*)d_in[5];
    const float* k_values      = (const float*)d_in[6];
    float* out = (float*)d_out;

    const size_t feat_bytes = (size_t)NPTS * FIN * sizeof(_Float16);           // 2.56 MB
    const size_t pts4_bytes = (size_t)NPTS * sizeof(float4);                   // 0.64 MB
    const size_t rs_bytes   = ((size_t)(MOUT + 1) * sizeof(int) + 15) & ~15ul; // 160 KB
    const size_t full_bytes = feat_bytes + pts4_bytes + rs_bytes;              // ~3.4 MB

    if (ws_size >= full_bytes) {
        char* p = (char*)d_ws;
        _Float16* feat_h    = (_Float16*)p;  p += feat_bytes;
        float4*   points4   = (float4*)p;    p += pts4_bytes;
        int*      row_start = (int*)p;

        preprocess_all<<<PRE_BLKS, 256, 0, stream>>>(
            features, feat_h, points, points4, seg_ids, row_start);
        kpconv_fused_mfma<<<MOUT / 16, 256, 0, stream>>>(
            points4, feat_h, output_points, nbr_idx, row_start,
            k_points, k_values, out);
    } else {
        unsigned short* agg_g = (unsigned short*)d_ws;   // needs 38.4 MB
        kpconv_agg_mfma<<<MOUT / 4, 256, 0, stream>>>(
            points, features, output_points, nbr_idx, seg_ids, k_points, agg_g);
        kpconv_gemm<<<MOUT / 32, 256, 0, stream>>>(agg_g, k_values, out);
    }
}

// Round 11
// 125.367 us; speedup vs baseline: 1.4914x; 1.4914x over previous
//
#include <hip/hip_runtime.h>

typedef __attribute__((ext_vector_type(8))) short bf16x8;
typedef __attribute__((ext_vector_type(8))) _Float16 f16x8;
typedef __attribute__((ext_vector_type(4))) float f32x4;
typedef __attribute__((ext_vector_type(4))) _Float16 f16x4;

#define NPTS   40000
#define MOUT   40000
#define EDG    500000
#define FIN    32
#define COUT   64
#define KP     15
#define KFDIM  (KP * FIN)          // 480
#define EXTENT 0.6f

#define FEAT_BLKS  (NPTS * FIN / 1024)            // 1250
#define PTS_BLKS   ((NPTS + 255) / 256)           // 157
#define ROW_BLKS   ((EDG + 255) / 256)            // 1954
#define PRE_BLKS   (FEAT_BLKS + PTS_BLKS + ROW_BLKS)

__device__ __forceinline__ short f2bf(float x) {
    union { float f; unsigned u; } v; v.f = x;
    unsigned r = (v.u + 0x7fffu + ((v.u >> 16) & 1u)) >> 16;
    return (short)r;
}

// ============================================================================
// Preprocess (ONE launch, branch by block range):
//   [0, 1250)      features f32 -> f16
//   [1250, 1407)   points -> float4 pad
//   [1407, 3361)   CSR row starts via scatter (disjoint ranges, no atomics)
// ============================================================================
__global__ __launch_bounds__(256) void preprocess_all(
    const float* __restrict__ features, _Float16* __restrict__ feat_h,
    const float* __restrict__ pts, float4* __restrict__ p4,
    const int* __restrict__ seg_ids, int* __restrict__ row_start)
{
    const int bid = blockIdx.x;
    if (bid < FEAT_BLKS) {
        const int i = (bid * 256 + threadIdx.x) * 4;
        const float4 v = *(const float4*)(features + i);
        feat_h[i + 0] = (_Float16)v.x;
        feat_h[i + 1] = (_Float16)v.y;
        feat_h[i + 2] = (_Float16)v.z;
        feat_h[i + 3] = (_Float16)v.w;
    } else if (bid < FEAT_BLKS + PTS_BLKS) {
        const int i = (bid - FEAT_BLKS) * 256 + threadIdx.x;
        if (i < NPTS) {
            const float* p = pts + 3 * i;
            p4[i] = make_float4(p[0], p[1], p[2], 0.f);
        }
    } else {
        const int e = (bid - FEAT_BLKS - PTS_BLKS) * 256 + threadIdx.x;
        if (e >= EDG) return;
        const int cur  = seg_ids[e];
        const int prev = (e == 0) ? -1 : seg_ids[e - 1];
        for (int m = prev + 1; m <= cur; ++m) row_start[m] = e;
        if (e == EDG - 1)
            for (int m = cur + 1; m <= MOUT; ++m) row_start[m] = EDG;
    }
}

// ============================================================================
// Kernel A (R9-proven structure): MFMA aggregation, K=16 f16, one wave per
// segment, CSR row_start (no LDS / no barrier / no binary search). Output
// now stored as f16 (1-op cvt vs 4-op manual bf16 round).
// DO NOT fuse the gemm into this kernel and DO NOT hold W fragments across
// the gather loop: R3/R5/R10 all spilled that way (R10: +150 MB scratch).
// ============================================================================
__global__ __launch_bounds__(256, 8) void kpconv_agg_mfma16(
    const float4* __restrict__ points4,
    const _Float16* __restrict__ feat_h,
    const float* __restrict__ output_points,
    const int*   __restrict__ nbr_idx,
    const int*   __restrict__ row_start,
    const float* __restrict__ k_points,
    _Float16* __restrict__ agg_g)
{
    const int tid  = threadIdx.x;
    const int wave = tid >> 6;
    const int lane = tid & 63;
    const int quad = lane >> 4;
    const int l16  = lane & 15;

    const int m = blockIdx.x * 4 + wave;
    const int e0 = row_start[m], e1 = row_start[m + 1];

    const float ox = output_points[m * 3 + 0];
    const float oy = output_points[m * 3 + 1];
    const float oz = output_points[m * 3 + 2];

    const int myk = l16 < KP ? l16 : 0;
    const float kpx = k_points[myk * 3 + 0];
    const float kpy = k_points[myk * 3 + 1];
    const float kpz = k_points[myk * 3 + 2];
    const float inv_ext = 1.f / EXTENT;

    f32x4 c_lo = {0.f, 0.f, 0.f, 0.f};
    f32x4 c_hi = {0.f, 0.f, 0.f, 0.f};

    for (int es = e0; es < e1; es += 16) {
        const int last = e1 - 1;
        const int ebase = es + quad * 4;

        int nb[4];
        #pragma unroll
        for (int j = 0; j < 4; ++j) {
            const int e = ebase + j;
            nb[j] = nbr_idx[e < e1 ? e : last];   // clamp; w=0 for tails
        }

        f16x4 afrag, blo, bhi;
        #pragma unroll
        for (int j = 0; j < 4; ++j) {
            const float4 p = points4[nb[j]];
            const float rx = p.x - ox;
            const float ry = p.y - oy;
            const float rz = p.z - oz;
            const float dx = rx - kpx, dy = ry - kpy, dz = rz - kpz;
            const float d2 = dx * dx + dy * dy + dz * dz;
            float w = 1.f - sqrtf(d2) * inv_ext;
            w = w > 0.f ? w : 0.f;
            if (l16 >= KP || ebase + j >= e1) w = 0.f;
            afrag[j] = (_Float16)w;
        }

        #pragma unroll
        for (int j = 0; j < 4; ++j) {
            const _Float16* fp = feat_h + nb[j] * FIN + l16;
            blo[j] = fp[0];
            bhi[j] = fp[16];
        }

        c_lo = __builtin_amdgcn_mfma_f32_16x16x16f16(afrag, blo, c_lo, 0, 0, 0);
        c_hi = __builtin_amdgcn_mfma_f32_16x16x16f16(afrag, bhi, c_hi, 0, 0, 0);
    }

    // D layout: col = lane&15 (= f), row = quad*4 + r (= kpoint)
    _Float16* dst = agg_g + (size_t)m * KFDIM;
    #pragma unroll
    for (int r = 0; r < 4; ++r) {
        const int krow = quad * 4 + r;
        if (krow < KP) {
            dst[krow * FIN + l16]      = (_Float16)c_lo[r];
            dst[krow * FIN + 16 + l16] = (_Float16)c_hi[r];
        }
    }
}

// ============================================================================
// Kernel B: out = agg[40000x480]_f16 x W[480x64] via mfma 16x16x32_f16.
// Wave = 32 rows x 16 cols, block = 32 rows x 64 cols, grid 1250.
// ============================================================================
__global__ __launch_bounds__(256, 4) void kpconv_gemm(
    const _Float16* __restrict__ agg_g,
    const float* __restrict__ k_values,
    float* __restrict__ out)
{
    const int tid  = threadIdx.x;
    const int wave = tid >> 6;
    const int lane = tid & 63;
    const int quad = lane >> 4;
    const int l16  = lane & 15;
    const int m0   = blockIdx.x * 32;
    const int bcol = wave * 16 + l16;

    f16x8 bfr[15];
    #pragma unroll
    for (int s = 0; s < 15; ++s) {
        #pragma unroll
        for (int j = 0; j < 8; ++j)
            bfr[s][j] = (_Float16)k_values[(32 * s + quad * 8 + j) * COUT + bcol];
    }

    const _Float16* arow0 = agg_g + (size_t)(m0 + l16) * KFDIM + quad * 8;
    const _Float16* arow1 = arow0 + 16 * KFDIM;

    f32x4 c0 = {0.f, 0.f, 0.f, 0.f};
    f32x4 c1 = {0.f, 0.f, 0.f, 0.f};
    #pragma unroll
    for (int s = 0; s < 15; ++s) {
        const f16x8 a0 = *(const f16x8*)(arow0 + 32 * s);
        const f16x8 a1 = *(const f16x8*)(arow1 + 32 * s);
        c0 = __builtin_amdgcn_mfma_f32_16x16x32_f16(a0, bfr[s], c0, 0, 0, 0);
        c1 = __builtin_amdgcn_mfma_f32_16x16x32_f16(a1, bfr[s], c1, 0, 0, 0);
    }

    // C/D layout: col = lane&15, row = quad*4 + reg
    #pragma unroll
    for (int r = 0; r < 4; ++r) {
        out[(m0 + quad * 4 + r) * COUT + bcol]      = c0[r];
        out[(m0 + 16 + quad * 4 + r) * COUT + bcol] = c1[r];
    }
}

// ============================================================================
// Fallback (small ws, needs only 38.4 MB): K=32 bf16 MFMA agg with in-kernel
// binary search + f32 feature loads; stores f16 so it shares kpconv_gemm.
// ============================================================================
__global__ __launch_bounds__(256, 4) void kpconv_agg_fallback(
    const float* __restrict__ points,
    const float* __restrict__ features,
    const float* __restrict__ output_points,
    const int*   __restrict__ nbr_idx,
    const int*   __restrict__ seg_ids,
    const float* __restrict__ k_points,
    _Float16* __restrict__ agg_g)
{
    __shared__ int seg_start[5];

    const int tid  = threadIdx.x;
    const int m0   = blockIdx.x * 4;

    if (tid <= 4) {
        const int target = m0 + tid;
        int lo = 0, hi = EDG;
        while (lo < hi) {
            int mid = (lo + hi) >> 1;
            if (seg_ids[mid] < target) lo = mid + 1; else hi = mid;
        }
        seg_start[tid] = lo;
    }
    __syncthreads();

    const int wave = tid >> 6;
    const int lane = tid & 63;
    const int quad = lane >> 4;
    const int l16  = lane & 15;

    const int m = m0 + wave;
    const float ox = output_points[m * 3 + 0];
    const float oy = output_points[m * 3 + 1];
    const float oz = output_points[m * 3 + 2];

    const int myk = l16 < KP ? l16 : 0;
    const float kpx = k_points[myk * 3 + 0];
    const float kpy = k_points[myk * 3 + 1];
    const float kpz = k_points[myk * 3 + 2];
    const float inv_ext = 1.f / EXTENT;

    const int e0 = seg_start[wave], e1 = seg_start[wave + 1];

    f32x4 c_lo = {0.f, 0.f, 0.f, 0.f};
    f32x4 c_hi = {0.f, 0.f, 0.f, 0.f};

    for (int es = e0; es < e1; es += 32) {
        const int last = e1 - 1;
        const int ebase = es + quad * 8;

        int nb[8];
        #pragma unroll
        for (int j = 0; j < 8; ++j) {
            const int e = ebase + j;
            nb[j] = nbr_idx[e < e1 ? e : last];
        }

        bf16x8 afrag, blo, bhi;
        #pragma unroll
        for (int j = 0; j < 8; ++j) {
            const float* pp = points + nb[j] * 3;
            const float rx = pp[0] - ox;
            const float ry = pp[1] - oy;
            const float rz = pp[2] - oz;
            const float dx = rx - kpx, dy = ry - kpy, dz = rz - kpz;
            const float d2 = dx * dx + dy * dy + dz * dz;
            float w = 1.f - sqrtf(d2) * inv_ext;
            w = w > 0.f ? w : 0.f;
            if (l16 >= KP || ebase + j >= e1) w = 0.f;
            afrag[j] = f2bf(w);
        }

        #pragma unroll
        for (int j = 0; j < 8; ++j) {
            const float* fp = features + nb[j] * FIN + l16;
            blo[j] = f2bf(fp[0]);
            bhi[j] = f2bf(fp[16]);
        }

        c_lo = __builtin_amdgcn_mfma_f32_16x16x32_bf16(afrag, blo, c_lo, 0, 0, 0);
        c_hi = __builtin_amdgcn_mfma_f32_16x16x32_bf16(afrag, bhi, c_hi, 0, 0, 0);
    }

    _Float16* dst = agg_g + (size_t)m * KFDIM;
    #pragma unroll
    for (int r = 0; r < 4; ++r) {
        const int krow = quad * 4 + r;
        if (krow < KP) {
            dst[krow * FIN + l16]      = (_Float16)c_lo[r];
            dst[krow * FIN + 16 + l16] = (_Float16)c_hi[r];
        }
    }
}

extern "C" void kernel_launch(void* const* d_in, const int* in_sizes, int n_in,
                              void* d_out, int out_size, void* d_ws, size_t ws_size,
                              hipStream_t stream) {
    const float* points        = (const float*)d_in[0];
    const float* features      = (const float*)d_in[1];
    const float* output_points = (const float*)d_in[2];
    const int*   nbr_idx       = (const int*)d_in[3];
    const int*   seg_ids       = (const int*)d_in[4];
    const float* k_points      = (const float*)d_in[5];
    const float* k_values      = (const float*)d_in[6];
    float* out = (float*)d_out;

    const size_t feat_bytes = (size_t)NPTS * FIN * sizeof(_Float16);           // 2.56 MB
    const size_t pts4_bytes = (size_t)NPTS * sizeof(float4);                   // 0.64 MB
    const size_t rs_bytes   = ((size_t)(MOUT + 1) * sizeof(int) + 15) & ~15ul; // 160 KB
    const size_t agg_bytes  = (size_t)MOUT * KFDIM * sizeof(_Float16);         // 38.4 MB
    const size_t full_bytes = feat_bytes + pts4_bytes + rs_bytes + agg_bytes;  // ~41.8 MB

    if (ws_size >= full_bytes) {
        char* p = (char*)d_ws;
        _Float16* feat_h    = (_Float16*)p;  p += feat_bytes;
        float4*   points4   = (float4*)p;    p += pts4_bytes;
        int*      row_start = (int*)p;       p += rs_bytes;
        _Float16* agg_g     = (_Float16*)p;

        preprocess_all<<<PRE_BLKS, 256, 0, stream>>>(
            features, feat_h, points, points4, seg_ids, row_start);
        kpconv_agg_mfma16<<<MOUT / 4, 256, 0, stream>>>(
            points4, feat_h, output_points, nbr_idx, row_start, k_points, agg_g);
        kpconv_gemm<<<MOUT / 32, 256, 0, stream>>>(agg_g, k_values, out);
    } else {
        _Float16* agg_g = (_Float16*)d_ws;   // needs 38.4 MB
        kpconv_agg_fallback<<<MOUT / 4, 256, 0, stream>>>(
            points, features, output_points, nbr_idx, seg_ids, k_points, agg_g);
        kpconv_gemm<<<MOUT / 32, 256, 0, stream>>>(agg_g, k_values, out);
    }
}

// Round 12
// 117.380 us; speedup vs baseline: 1.5929x; 1.0680x over previous
//
#include <hip/hip_runtime.h>

typedef __attribute__((ext_vector_type(8))) short bf16x8;
typedef __attribute__((ext_vector_type(8))) _Float16 f16x8;
typedef __attribute__((ext_vector_type(4))) float f32x4;
typedef __attribute__((ext_vector_type(4))) _Float16 f16x4;
typedef __attribute__((ext_vector_type(2))) _Float16 f16x2;

#define NPTS   40000
#define MOUT   40000
#define EDG    500000
#define FIN    32
#define COUT   64
#define KP     15
#define KFDIM  (KP * FIN)          // 480
#define EXTENT 0.6f

// LDS per wave: feat tile 16 rows x 112B (stride 112 -> <=2-way banks for
// b128 writes and b32 frag reads) + w tile 16 rows x 40B (8B-aligned b64
// frag reads, <=2-way). 2432 B/wave, 9728 B/block.
#define FSTRIDE 112
#define WSTRIDE 40
#define WAVE_LDS (16 * FSTRIDE + 16 * WSTRIDE)    // 2432 (16-mult)

#define FEAT_BLKS  (NPTS * FIN / 1024)            // 1250
#define PTS_BLKS   ((NPTS + 255) / 256)           // 157
#define OP_BLKS    ((MOUT + 255) / 256)           // 157
#define ROW_BLKS   ((EDG + 255) / 256)            // 1954
#define WT_BLKS    (KFDIM * COUT / 256)           // 120
#define PRE_BLKS   (FEAT_BLKS + PTS_BLKS + OP_BLKS + ROW_BLKS + WT_BLKS)

__device__ __forceinline__ short f2bf(float x) {
    union { float f; unsigned u; } v; v.f = x;
    unsigned r = (v.u + 0x7fffu + ((v.u >> 16) & 1u)) >> 16;
    return (short)r;
}

// ============================================================================
// Preprocess (ONE launch, branch by block range):
//  feat:  f32 -> f16, channel pairs interleaved: feat_i[p][2f'+h] = feat[p][f'+16h]
//  pts:   points -> float4 pad
//  op:    output_points -> float4 pad
//  row:   CSR row starts via scatter (disjoint ranges, no atomics)
//  wt:    k_values f32 -> f16, transposed+interleaved: w_t[c][k*32+2f'+h] =
//         W[k*32+f'+16h][c]  (same kf order as agg_i -> contraction matches)
// ============================================================================
__global__ __launch_bounds__(256) void preprocess_all(
    const float* __restrict__ features, _Float16* __restrict__ feat_i,
    const float* __restrict__ pts, float4* __restrict__ p4,
    const float* __restrict__ opts, float4* __restrict__ op4,
    const int* __restrict__ seg_ids, int* __restrict__ row_start,
    const float* __restrict__ k_values, _Float16* __restrict__ w_t)
{
    const int bid = blockIdx.x;
    if (bid < FEAT_BLKS) {
        const int d0 = (bid * 256 + threadIdx.x) * 4;
        #pragma unroll
        for (int u = 0; u < 4; ++u) {
            const int d = d0 + u;
            const int p = d >> 5, q = d & 31;
            const int fp = q >> 1, h = q & 1;
            feat_i[d] = (_Float16)features[p * FIN + fp + 16 * h];
        }
    } else if (bid < FEAT_BLKS + PTS_BLKS) {
        const int i = (bid - FEAT_BLKS) * 256 + threadIdx.x;
        if (i < NPTS) {
            const float* p = pts + 3 * i;
            p4[i] = make_float4(p[0], p[1], p[2], 0.f);
        }
    } else if (bid < FEAT_BLKS + PTS_BLKS + OP_BLKS) {
        const int i = (bid - FEAT_BLKS - PTS_BLKS) * 256 + threadIdx.x;
        if (i < MOUT) {
            const float* p = opts + 3 * i;
            op4[i] = make_float4(p[0], p[1], p[2], 0.f);
        }
    } else if (bid < FEAT_BLKS + PTS_BLKS + OP_BLKS + ROW_BLKS) {
        const int e = (bid - FEAT_BLKS - PTS_BLKS - OP_BLKS) * 256 + threadIdx.x;
        if (e >= EDG) return;
        const int cur  = seg_ids[e];
        const int prev = (e == 0) ? -1 : seg_ids[e - 1];
        for (int m = prev + 1; m <= cur; ++m) row_start[m] = e;
        if (e == EDG - 1)
            for (int m = cur + 1; m <= MOUT; ++m) row_start[m] = EDG;
    } else {
        const int d = (bid - FEAT_BLKS - PTS_BLKS - OP_BLKS - ROW_BLKS) * 256
                      + threadIdx.x;                 // 0 .. 30719
        const int c = d / KFDIM, r = d % KFDIM;
        const int k = r >> 5, q = r & 31;
        const int fp = q >> 1, h = q & 1;
        w_t[d] = (_Float16)k_values[(k * FIN + fp + 16 * h) * COUT + c];
    }
}

// ============================================================================
// Kernel A: edge-parallel MFMA aggregation. One wave per segment, K=16 steps.
// Per step only THREE divergent-gather VMEM instructions (idx, point, 16B
// feat chunk — lane owns edge lane>>2), then a wave-private LDS transpose
// into fragment order (no barrier needed). R11's version issued 16 gathers
// per step — that address-processing was the measured bottleneck.
//   A[kpoint][edge]: lane&15, quad*4+j (w tile, ds_read_b64)
//   B[edge][chan] : interleaved pair per ds_read_b32
//   D: col = chan-pair (lane&15), row = quad*4+r (kpoint) -> b32 stores.
// (256,6): cap 85 vs natural ~55 — 1.5x headroom (R3/R5/R10 spill lesson).
// ============================================================================
__global__ __launch_bounds__(256, 6) void kpconv_agg_edge(
    const float4* __restrict__ points4,
    const _Float16* __restrict__ feat_i,
    const float4* __restrict__ op4,
    const int*   __restrict__ nbr_idx,
    const int*   __restrict__ row_start,
    const float* __restrict__ k_points,
    _Float16* __restrict__ agg_g)
{
    __shared__ __align__(16) unsigned char smem[4 * WAVE_LDS];

    const int tid  = threadIdx.x;
    const int wave = tid >> 6;
    const int lane = tid & 63;
    const int quad = lane >> 4;
    const int l16  = lane & 15;
    const int esl  = lane >> 2;       // edge slot 0..15 (edge-parallel role)
    const int kg   = lane & 3;        // kgroup / feat-chunk index

    unsigned char* fbase = smem + wave * WAVE_LDS;
    unsigned char* wbase = fbase + 16 * FSTRIDE;

    const int m  = blockIdx.x * 4 + wave;
    const int e0 = row_start[m];
    const int e1 = row_start[m + 1];
    const float4 o = op4[m];

    // per-lane kernel points (kgroup role): kpoints kg*4+t
    float kx[4], ky[4], kz[4];
    #pragma unroll
    for (int t = 0; t < 4; ++t) {
        const int k  = kg * 4 + t;
        const int kk = k < KP ? k : 0;
        kx[t] = k_points[kk * 3 + 0];
        ky[t] = k_points[kk * 3 + 1];
        kz[t] = k_points[kk * 3 + 2];
    }
    const float inv_ext = 1.f / EXTENT;

    f32x4 c_lo = {0.f, 0.f, 0.f, 0.f};
    f32x4 c_hi = {0.f, 0.f, 0.f, 0.f};

    for (int es = e0; es < e1; es += 16) {
        const int e  = es + esl;
        const int nb = nbr_idx[e < e1 ? e : e1 - 1];   // gather 1

        // stage this edge's 16B feature chunk (gather 2)
        const uint4 fc = *(const uint4*)(feat_i + nb * FIN + kg * 8);
        *(uint4*)(fbase + esl * FSTRIDE + kg * 16) = fc;

        // weights for edge esl, kpoints kg*4..kg*4+3 (gather 3)
        const float4 p = points4[nb];
        const float rx = p.x - o.x, ry = p.y - o.y, rz = p.z - o.z;
        const bool evalid = e < e1;
        #pragma unroll
        for (int t = 0; t < 4; ++t) {
            const float dx = rx - kx[t], dy = ry - ky[t], dz = rz - kz[t];
            float w = 1.f - sqrtf(dx * dx + dy * dy + dz * dz) * inv_ext;
            w = w > 0.f ? w : 0.f;
            if (!evalid || (kg * 4 + t) >= KP) w = 0.f;
            *(_Float16*)(wbase + (kg * 4 + t) * WSTRIDE + esl * 2) = (_Float16)w;
        }

        // fragments from LDS (wave-private: no barrier, lgkmcnt only)
        const f16x4 af = *(const f16x4*)(wbase + l16 * WSTRIDE + quad * 8);
        f16x2 w2[4];
        #pragma unroll
        for (int j = 0; j < 4; ++j)
            w2[j] = *(const f16x2*)(fbase + (quad * 4 + j) * FSTRIDE + l16 * 4);
        const f16x4 blo = {w2[0][0], w2[1][0], w2[2][0], w2[3][0]};
        const f16x4 bhi = {w2[0][1], w2[1][1], w2[2][1], w2[3][1]};

        c_lo = __builtin_amdgcn_mfma_f32_16x16x16f16(af, blo, c_lo, 0, 0, 0);
        c_hi = __builtin_amdgcn_mfma_f32_16x16x16f16(af, bhi, c_hi, 0, 0, 0);
    }

    // D: col=chan-pair l16, row=quad*4+r (kpoint); store packed (lo,hi)
    _Float16* dst = agg_g + (size_t)m * KFDIM;
    #pragma unroll
    for (int r = 0; r < 4; ++r) {
        const int krow = quad * 4 + r;
        if (krow < KP) {
            f16x2 v = {(_Float16)c_lo[r], (_Float16)c_hi[r]};
            *(f16x2*)(dst + krow * FIN + 2 * l16) = v;
        }
    }
}

// ============================================================================
// Kernel B: out = agg_i[40000x480] x W (both f16, same interleaved kf order).
// B-fragments now straight b128 loads from pre-transposed w_t[c][kf].
// ============================================================================
__global__ __launch_bounds__(256, 4) void kpconv_gemm_i(
    const _Float16* __restrict__ agg_g,
    const _Float16* __restrict__ w_t,
    float* __restrict__ out)
{
    const int tid  = threadIdx.x;
    const int wave = tid >> 6;
    const int lane = tid & 63;
    const int quad = lane >> 4;
    const int l16  = lane & 15;
    const int m0   = blockIdx.x * 32;
    const int bcol = wave * 16 + l16;

    f16x8 bfr[15];
    const _Float16* wrow = w_t + (size_t)bcol * KFDIM + quad * 8;
    #pragma unroll
    for (int s = 0; s < 15; ++s)
        bfr[s] = *(const f16x8*)(wrow + 32 * s);

    const _Float16* arow0 = agg_g + (size_t)(m0 + l16) * KFDIM + quad * 8;
    const _Float16* arow1 = arow0 + 16 * KFDIM;

    f32x4 c0 = {0.f, 0.f, 0.f, 0.f};
    f32x4 c1 = {0.f, 0.f, 0.f, 0.f};
    #pragma unroll
    for (int s = 0; s < 15; ++s) {
        const f16x8 a0 = *(const f16x8*)(arow0 + 32 * s);
        const f16x8 a1 = *(const f16x8*)(arow1 + 32 * s);
        c0 = __builtin_amdgcn_mfma_f32_16x16x32_f16(a0, bfr[s], c0, 0, 0, 0);
        c1 = __builtin_amdgcn_mfma_f32_16x16x32_f16(a1, bfr[s], c1, 0, 0, 0);
    }

    #pragma unroll
    for (int r = 0; r < 4; ++r) {
        out[(m0 + quad * 4 + r) * COUT + bcol]      = c0[r];
        out[(m0 + 16 + quad * 4 + r) * COUT + bcol] = c1[r];
    }
}

// ============================================================================
// Fallback (small ws, 38.4 MB): R11's binary-search K=32 agg + plain-order
// gemm reading f32 k_values.
// ============================================================================
__global__ __launch_bounds__(256, 4) void kpconv_agg_fallback(
    const float* __restrict__ points,
    const float* __restrict__ features,
    const float* __restrict__ output_points,
    const int*   __restrict__ nbr_idx,
    const int*   __restrict__ seg_ids,
    const float* __restrict__ k_points,
    _Float16* __restrict__ agg_g)
{
    __shared__ int seg_start[5];

    const int tid = threadIdx.x;
    const int m0  = blockIdx.x * 4;

    if (tid <= 4) {
        const int target = m0 + tid;
        int lo = 0, hi = EDG;
        while (lo < hi) {
            int mid = (lo + hi) >> 1;
            if (seg_ids[mid] < target) lo = mid + 1; else hi = mid;
        }
        seg_start[tid] = lo;
    }
    __syncthreads();

    const int wave = tid >> 6;
    const int lane = tid & 63;
    const int quad = lane >> 4;
    const int l16  = lane & 15;

    const int m = m0 + wave;
    const float ox = output_points[m * 3 + 0];
    const float oy = output_points[m * 3 + 1];
    const float oz = output_points[m * 3 + 2];

    const int myk = l16 < KP ? l16 : 0;
    const float kpx = k_points[myk * 3 + 0];
    const float kpy = k_points[myk * 3 + 1];
    const float kpz = k_points[myk * 3 + 2];
    const float inv_ext = 1.f / EXTENT;

    const int e0 = seg_start[wave], e1 = seg_start[wave + 1];

    f32x4 c_lo = {0.f, 0.f, 0.f, 0.f};
    f32x4 c_hi = {0.f, 0.f, 0.f, 0.f};

    for (int es = e0; es < e1; es += 32) {
        const int last = e1 - 1;
        const int ebase = es + quad * 8;

        int nb[8];
        #pragma unroll
        for (int j = 0; j < 8; ++j) {
            const int e = ebase + j;
            nb[j] = nbr_idx[e < e1 ? e : last];
        }

        bf16x8 afrag, blo, bhi;
        #pragma unroll
        for (int j = 0; j < 8; ++j) {
            const float* pp = points + nb[j] * 3;
            const float rx = pp[0] - ox;
            const float ry = pp[1] - oy;
            const float rz = pp[2] - oz;
            const float dx = rx - kpx, dy = ry - kpy, dz = rz - kpz;
            const float d2 = dx * dx + dy * dy + dz * dz;
            float w = 1.f - sqrtf(d2) * inv_ext;
            w = w > 0.f ? w : 0.f;
            if (l16 >= KP || ebase + j >= e1) w = 0.f;
            afrag[j] = f2bf(w);
        }

        #pragma unroll
        for (int j = 0; j < 8; ++j) {
            const float* fp = features + nb[j] * FIN + l16;
            blo[j] = f2bf(fp[0]);
            bhi[j] = f2bf(fp[16]);
        }

        c_lo = __builtin_amdgcn_mfma_f32_16x16x32_bf16(afrag, blo, c_lo, 0, 0, 0);
        c_hi = __builtin_amdgcn_mfma_f32_16x16x32_bf16(afrag, bhi, c_hi, 0, 0, 0);
    }

    _Float16* dst = agg_g + (size_t)m * KFDIM;
    #pragma unroll
    for (int r = 0; r < 4; ++r) {
        const int krow = quad * 4 + r;
        if (krow < KP) {
            dst[krow * FIN + l16]      = (_Float16)c_lo[r];
            dst[krow * FIN + 16 + l16] = (_Float16)c_hi[r];
        }
    }
}

__global__ __launch_bounds__(256, 4) void kpconv_gemm_plain(
    const _Float16* __restrict__ agg_g,
    const float* __restrict__ k_values,
    float* __restrict__ out)
{
    const int tid  = threadIdx.x;
    const int wave = tid >> 6;
    const int lane = tid & 63;
    const int quad = lane >> 4;
    const int l16  = lane & 15;
    const int m0   = blockIdx.x * 32;
    const int bcol = wave * 16 + l16;

    f16x8 bfr[15];
    #pragma unroll
    for (int s = 0; s < 15; ++s) {
        #pragma unroll
        for (int j = 0; j < 8; ++j)
            bfr[s][j] = (_Float16)k_values[(32 * s + quad * 8 + j) * COUT + bcol];
    }

    const _Float16* arow0 = agg_g + (size_t)(m0 + l16) * KFDIM + quad * 8;
    const _Float16* arow1 = arow0 + 16 * KFDIM;

    f32x4 c0 = {0.f, 0.f, 0.f, 0.f};
    f32x4 c1 = {0.f, 0.f, 0.f, 0.f};
    #pragma unroll
    for (int s = 0; s < 15; ++s) {
        const f16x8 a0 = *(const f16x8*)(arow0 + 32 * s);
        const f16x8 a1 = *(const f16x8*)(arow1 + 32 * s);
        c0 = __builtin_amdgcn_mfma_f32_16x16x32_f16(a0, bfr[s], c0, 0, 0, 0);
        c1 = __builtin_amdgcn_mfma_f32_16x16x32_f16(a1, bfr[s], c1, 0, 0, 0);
    }

    #pragma unroll
    for (int r = 0; r < 4; ++r) {
        out[(m0 + quad * 4 + r) * COUT + bcol]      = c0[r];
        out[(m0 + 16 + quad * 4 + r) * COUT + bcol] = c1[r];
    }
}

extern "C" void kernel_launch(void* const* d_in, const int* in_sizes, int n_in,
                              void* d_out, int out_size, void* d_ws, size_t ws_size,
                              hipStream_t stream) {
    const float* points        = (const float*)d_in[0];
    const float* features      = (const float*)d_in[1];
    const float* output_points = (const float*)d_in[2];
    const int*   nbr_idx       = (const int*)d_in[3];
    const int*   seg_ids       = (const int*)d_in[4];
    const float* k_points      = (const float*)d_in[5];
    const float* k_values      = (const float*)d_in[6];
    float* out = (float*)d_out;

    const size_t feat_bytes = (size_t)NPTS * FIN * sizeof(_Float16);           // 2.56 MB
    const size_t pts4_bytes = (size_t)NPTS * sizeof(float4);                   // 0.64 MB
    const size_t op4_bytes  = (size_t)MOUT * sizeof(float4);                   // 0.64 MB
    const size_t rs_bytes   = ((size_t)(MOUT + 1) * sizeof(int) + 15) & ~15ul; // 160 KB
    const size_t wt_bytes   = (size_t)KFDIM * COUT * sizeof(_Float16);         // 60 KB
    const size_t agg_bytes  = (size_t)MOUT * KFDIM * sizeof(_Float16);         // 38.4 MB
    const size_t full_bytes = feat_bytes + pts4_bytes + op4_bytes + rs_bytes
                            + wt_bytes + agg_bytes;                            // ~42.5 MB

    if (ws_size >= full_bytes) {
        char* p = (char*)d_ws;
        _Float16* feat_i    = (_Float16*)p;  p += feat_bytes;
        float4*   points4   = (float4*)p;    p += pts4_bytes;
        float4*   op4       = (float4*)p;    p += op4_bytes;
        int*      row_start = (int*)p;       p += rs_bytes;
        _Float16* w_t       = (_Float16*)p;  p += wt_bytes;
        _Float16* agg_g     = (_Float16*)p;

        preprocess_all<<<PRE_BLKS, 256, 0, stream>>>(
            features, feat_i, points, points4, output_points, op4,
            seg_ids, row_start, k_values, w_t);
        kpconv_agg_edge<<<MOUT / 4, 256, 0, stream>>>(
            points4, feat_i, op4, nbr_idx, row_start, k_points, agg_g);
        kpconv_gemm_i<<<MOUT / 32, 256, 0, stream>>>(agg_g, w_t, out);
    } else {
        _Float16* agg_g = (_Float16*)d_ws;   // needs 38.4 MB
        kpconv_agg_fallback<<<MOUT / 4, 256, 0, stream>>>(
            points, features, output_points, nbr_idx, seg_ids, k_points, agg_g);
        kpconv_gemm_plain<<<MOUT / 32, 256, 0, stream>>>(agg_g, k_values, out);
    }
}

// Round 13
// 106.866 us; speedup vs baseline: 1.7496x; 1.0984x over previous
//
#include <hip/hip_runtime.h>

typedef __attribute__((ext_vector_type(8))) short bf16x8;
typedef __attribute__((ext_vector_type(8))) _Float16 f16x8;
typedef __attribute__((ext_vector_type(4))) float f32x4;
typedef __attribute__((ext_vector_type(4))) _Float16 f16x4;
typedef __attribute__((ext_vector_type(2))) _Float16 f16x2;

#define NPTS   40000
#define MOUT   40000
#define EDG    500000
#define FIN    32
#define COUT   64
#define KP     15
#define KFDIM  (KP * FIN)          // 480
#define EXTENT 0.6f

// Phase-1 wave-private staging (R12-proven strides):
#define FSTRIDE 112
#define WSTRIDE 40
#define WAVE_LDS (16 * FSTRIDE + 16 * WSTRIDE)    // 2432 B/wave
// Block agg tile: 16 segments x 488 f16 (976B rows = 61*16B, conflict-free b128)
#define ASTR 488

#define FEAT_BLKS  (NPTS * FIN / 1024)            // 1250
#define PTS_BLKS   ((NPTS + 255) / 256)           // 157
#define OP_BLKS    ((MOUT + 255) / 256)           // 157
#define ROW_BLKS   ((EDG + 255) / 256)            // 1954
#define WT_BLKS    (KFDIM * COUT / 256)           // 120
#define PRE_BLKS   (FEAT_BLKS + PTS_BLKS + OP_BLKS + ROW_BLKS + WT_BLKS)

__device__ __forceinline__ short f2bf(float x) {
    union { float f; unsigned u; } v; v.f = x;
    unsigned r = (v.u + 0x7fffu + ((v.u >> 16) & 1u)) >> 16;
    return (short)r;
}

// ============================================================================
// Preprocess (ONE launch, branch by block range):
//  feat:  f32 -> f16, channel pairs interleaved: feat_i[p][2f'+h] = feat[p][f'+16h]
//  pts:   points -> float4 pad ;  op: output_points -> float4 pad
//  row:   CSR row starts via scatter (disjoint ranges, no atomics)
//  wt:    k_values f32 -> f16, transposed+interleaved: w_t[c][k*32+2f'+h] =
//         W[k*32+f'+16h][c]  (same kf order as the agg tile)
// ============================================================================
__global__ __launch_bounds__(256) void preprocess_all(
    const float* __restrict__ features, _Float16* __restrict__ feat_i,
    const float* __restrict__ pts, float4* __restrict__ p4,
    const float* __restrict__ opts, float4* __restrict__ op4,
    const int* __restrict__ seg_ids, int* __restrict__ row_start,
    const float* __restrict__ k_values, _Float16* __restrict__ w_t)
{
    const int bid = blockIdx.x;
    if (bid < FEAT_BLKS) {
        const int d0 = (bid * 256 + threadIdx.x) * 4;
        #pragma unroll
        for (int u = 0; u < 4; ++u) {
            const int d = d0 + u;
            const int p = d >> 5, q = d & 31;
            const int fp = q >> 1, h = q & 1;
            feat_i[d] = (_Float16)features[p * FIN + fp + 16 * h];
        }
    } else if (bid < FEAT_BLKS + PTS_BLKS) {
        const int i = (bid - FEAT_BLKS) * 256 + threadIdx.x;
        if (i < NPTS) {
            const float* p = pts + 3 * i;
            p4[i] = make_float4(p[0], p[1], p[2], 0.f);
        }
    } else if (bid < FEAT_BLKS + PTS_BLKS + OP_BLKS) {
        const int i = (bid - FEAT_BLKS - PTS_BLKS) * 256 + threadIdx.x;
        if (i < MOUT) {
            const float* p = opts + 3 * i;
            op4[i] = make_float4(p[0], p[1], p[2], 0.f);
        }
    } else if (bid < FEAT_BLKS + PTS_BLKS + OP_BLKS + ROW_BLKS) {
        const int e = (bid - FEAT_BLKS - PTS_BLKS - OP_BLKS) * 256 + threadIdx.x;
        if (e >= EDG) return;
        const int cur  = seg_ids[e];
        const int prev = (e == 0) ? -1 : seg_ids[e - 1];
        for (int m = prev + 1; m <= cur; ++m) row_start[m] = e;
        if (e == EDG - 1)
            for (int m = cur + 1; m <= MOUT; ++m) row_start[m] = EDG;
    } else {
        const int d = (bid - FEAT_BLKS - PTS_BLKS - OP_BLKS - ROW_BLKS) * 256
                      + threadIdx.x;                 // 0 .. 30719
        const int c = d / KFDIM, r = d % KFDIM;
        const int k = r >> 5, q = r & 31;
        const int fp = q >> 1, h = q & 1;
        w_t[d] = (_Float16)k_values[(k * FIN + fp + 16 * h) * COUT + c];
    }
}

// ============================================================================
// Fused kernel: block = 16 segments.
// Phase 1 (R12-proven edge-parallel agg, 4 segments/wave sequentially):
//   3 gather VMEM per 16-edge step + wave-private LDS transpose, 2 MFMAs.
//   D (col=chan-pair, row=kpoint) -> f16x2 stores into block agg tile.
// Barrier. Phase 2: 15x mfma 16x16x32_f16; A = ds_read_b128 from agg tile,
//   B = IN-LOOP b128 loads from w_t (L2-hot). NO B-fragment array held
//   across phase 1 — that pattern spilled in R3/R5/R10 (+150 MB scratch).
// (256,4): VGPR cap 128 vs natural ~60 peak. LDS 25.3 KB -> 6 blocks/CU.
// Spill tripwire: WRITE_SIZE must be ~10 MB (out only).
// ============================================================================
__global__ __launch_bounds__(256, 4) void kpconv_fused2(
    const float4* __restrict__ points4,
    const _Float16* __restrict__ feat_i,
    const float4* __restrict__ op4,
    const int*   __restrict__ nbr_idx,
    const int*   __restrict__ row_start,
    const float* __restrict__ k_points,
    const _Float16* __restrict__ w_t,
    float* __restrict__ out)
{
    __shared__ __align__(16) _Float16 aggT[16 * ASTR];          // 15616 B
    __shared__ __align__(16) unsigned char stage[4 * WAVE_LDS]; //  9728 B

    const int tid  = threadIdx.x;
    const int wave = tid >> 6;
    const int lane = tid & 63;
    const int quad = lane >> 4;
    const int l16  = lane & 15;
    const int esl  = lane >> 2;       // edge slot 0..15
    const int kg   = lane & 3;        // kgroup / feat-chunk index
    const int m0   = blockIdx.x * 16;

    unsigned char* fbase = stage + wave * WAVE_LDS;
    unsigned char* wbase = fbase + 16 * FSTRIDE;

    // per-lane kernel points (kgroup role)
    float kx[4], ky[4], kz[4];
    #pragma unroll
    for (int t = 0; t < 4; ++t) {
        const int k  = kg * 4 + t;
        const int kk = k < KP ? k : 0;
        kx[t] = k_points[kk * 3 + 0];
        ky[t] = k_points[kk * 3 + 1];
        kz[t] = k_points[kk * 3 + 2];
    }
    const float inv_ext = 1.f / EXTENT;

    // ---- Phase 1: 4 segments per wave ----
    for (int s4 = 0; s4 < 4; ++s4) {
        const int li = wave * 4 + s4;
        const int m  = m0 + li;
        const int e0 = row_start[m];
        const int e1 = row_start[m + 1];
        const float4 o = op4[m];

        f32x4 c_lo = {0.f, 0.f, 0.f, 0.f};
        f32x4 c_hi = {0.f, 0.f, 0.f, 0.f};

        for (int es = e0; es < e1; es += 16) {
            const int e  = es + esl;
            const int nb = nbr_idx[e < e1 ? e : e1 - 1];   // gather 1

            const uint4 fc = *(const uint4*)(feat_i + nb * FIN + kg * 8); // g2
            *(uint4*)(fbase + esl * FSTRIDE + kg * 16) = fc;

            const float4 p = points4[nb];                  // gather 3
            const float rx = p.x - o.x, ry = p.y - o.y, rz = p.z - o.z;
            const bool evalid = e < e1;
            #pragma unroll
            for (int t = 0; t < 4; ++t) {
                const float dx = rx - kx[t], dy = ry - ky[t], dz = rz - kz[t];
                float w = 1.f - sqrtf(dx * dx + dy * dy + dz * dz) * inv_ext;
                w = w > 0.f ? w : 0.f;
                if (!evalid || (kg * 4 + t) >= KP) w = 0.f;
                *(_Float16*)(wbase + (kg * 4 + t) * WSTRIDE + esl * 2) = (_Float16)w;
            }

            const f16x4 af = *(const f16x4*)(wbase + l16 * WSTRIDE + quad * 8);
            f16x2 w2[4];
            #pragma unroll
            for (int j = 0; j < 4; ++j)
                w2[j] = *(const f16x2*)(fbase + (quad * 4 + j) * FSTRIDE + l16 * 4);
            const f16x4 blo = {w2[0][0], w2[1][0], w2[2][0], w2[3][0]};
            const f16x4 bhi = {w2[0][1], w2[1][1], w2[2][1], w2[3][1]};

            c_lo = __builtin_amdgcn_mfma_f32_16x16x16f16(af, blo, c_lo, 0, 0, 0);
            c_hi = __builtin_amdgcn_mfma_f32_16x16x16f16(af, bhi, c_hi, 0, 0, 0);
        }

        // D -> agg tile row li (interleaved kf order): byte = k*64 + l16*4
        _Float16* dst = aggT + li * ASTR;
        #pragma unroll
        for (int r = 0; r < 4; ++r) {
            const int krow = quad * 4 + r;
            if (krow < KP) {
                f16x2 v = {(_Float16)c_lo[r], (_Float16)c_hi[r]};
                *(f16x2*)(dst + krow * 32 + 2 * l16) = v;
            }
        }
    }

    __syncthreads();

    // ---- Phase 2: C[16 segs x 16 cols] per wave, B in-loop from w_t ----
    const int bcol = wave * 16 + l16;
    const _Float16* wrow = w_t + (size_t)bcol * KFDIM + quad * 8;
    const _Float16* arow = aggT + l16 * ASTR + quad * 8;

    f32x4 c = {0.f, 0.f, 0.f, 0.f};
    #pragma unroll
    for (int s = 0; s < 15; ++s) {
        const f16x8 a = *(const f16x8*)(arow + 32 * s);
        const f16x8 b = *(const f16x8*)(wrow + 32 * s);
        c = __builtin_amdgcn_mfma_f32_16x16x32_f16(a, b, c, 0, 0, 0);
    }

    // C/D: col = lane&15 (-> bcol), row = quad*4 + r (= local segment)
    #pragma unroll
    for (int r = 0; r < 4; ++r)
        out[(m0 + quad * 4 + r) * COUT + bcol] = c[r];
}

// ============================================================================
// Fallback (small ws, needs 38.4 MB): binary-search K=32 agg + plain gemm.
// ============================================================================
__global__ __launch_bounds__(256, 4) void kpconv_agg_fallback(
    const float* __restrict__ points,
    const float* __restrict__ features,
    const float* __restrict__ output_points,
    const int*   __restrict__ nbr_idx,
    const int*   __restrict__ seg_ids,
    const float* __restrict__ k_points,
    _Float16* __restrict__ agg_g)
{
    __shared__ int seg_start[5];

    const int tid = threadIdx.x;
    const int m0  = blockIdx.x * 4;

    if (tid <= 4) {
        const int target = m0 + tid;
        int lo = 0, hi = EDG;
        while (lo < hi) {
            int mid = (lo + hi) >> 1;
            if (seg_ids[mid] < target) lo = mid + 1; else hi = mid;
        }
        seg_start[tid] = lo;
    }
    __syncthreads();

    const int wave = tid >> 6;
    const int lane = tid & 63;
    const int quad = lane >> 4;
    const int l16  = lane & 15;

    const int m = m0 + wave;
    const float ox = output_points[m * 3 + 0];
    const float oy = output_points[m * 3 + 1];
    const float oz = output_points[m * 3 + 2];

    const int myk = l16 < KP ? l16 : 0;
    const float kpx = k_points[myk * 3 + 0];
    const float kpy = k_points[myk * 3 + 1];
    const float kpz = k_points[myk * 3 + 2];
    const float inv_ext = 1.f / EXTENT;

    const int e0 = seg_start[wave], e1 = seg_start[wave + 1];

    f32x4 c_lo = {0.f, 0.f, 0.f, 0.f};
    f32x4 c_hi = {0.f, 0.f, 0.f, 0.f};

    for (int es = e0; es < e1; es += 32) {
        const int last = e1 - 1;
        const int ebase = es + quad * 8;

        int nb[8];
        #pragma unroll
        for (int j = 0; j < 8; ++j) {
            const int e = ebase + j;
            nb[j] = nbr_idx[e < e1 ? e : last];
        }

        bf16x8 afrag, blo, bhi;
        #pragma unroll
        for (int j = 0; j < 8; ++j) {
            const float* pp = points + nb[j] * 3;
            const float rx = pp[0] - ox;
            const float ry = pp[1] - oy;
            const float rz = pp[2] - oz;
            const float dx = rx - kpx, dy = ry - kpy, dz = rz - kpz;
            const float d2 = dx * dx + dy * dy + dz * dz;
            float w = 1.f - sqrtf(d2) * inv_ext;
            w = w > 0.f ? w : 0.f;
            if (l16 >= KP || ebase + j >= e1) w = 0.f;
            afrag[j] = f2bf(w);
        }

        #pragma unroll
        for (int j = 0; j < 8; ++j) {
            const float* fp = features + nb[j] * FIN + l16;
            blo[j] = f2bf(fp[0]);
            bhi[j] = f2bf(fp[16]);
        }

        c_lo = __builtin_amdgcn_mfma_f32_16x16x32_bf16(afrag, blo, c_lo, 0, 0, 0);
        c_hi = __builtin_amdgcn_mfma_f32_16x16x32_bf16(afrag, bhi, c_hi, 0, 0, 0);
    }

    _Float16* dst = agg_g + (size_t)m * KFDIM;
    #pragma unroll
    for (int r = 0; r < 4; ++r) {
        const int krow = quad * 4 + r;
        if (krow < KP) {
            dst[krow * FIN + l16]      = (_Float16)c_lo[r];
            dst[krow * FIN + 16 + l16] = (_Float16)c_hi[r];
        }
    }
}

__global__ __launch_bounds__(256, 4) void kpconv_gemm_plain(
    const _Float16* __restrict__ agg_g,
    const float* __restrict__ k_values,
    float* __restrict__ out)
{
    const int tid  = threadIdx.x;
    const int wave = tid >> 6;
    const int lane = tid & 63;
    const int quad = lane >> 4;
    const int l16  = lane & 15;
    const int m0   = blockIdx.x * 32;
    const int bcol = wave * 16 + l16;

    f16x8 bfr[15];
    #pragma unroll
    for (int s = 0; s < 15; ++s) {
        #pragma unroll
        for (int j = 0; j < 8; ++j)
            bfr[s][j] = (_Float16)k_values[(32 * s + quad * 8 + j) * COUT + bcol];
    }

    const _Float16* arow0 = agg_g + (size_t)(m0 + l16) * KFDIM + quad * 8;
    const _Float16* arow1 = arow0 + 16 * KFDIM;

    f32x4 c0 = {0.f, 0.f, 0.f, 0.f};
    f32x4 c1 = {0.f, 0.f, 0.f, 0.f};
    #pragma unroll
    for (int s = 0; s < 15; ++s) {
        const f16x8 a0 = *(const f16x8*)(arow0 + 32 * s);
        const f16x8 a1 = *(const f16x8*)(arow1 + 32 * s);
        c0 = __builtin_amdgcn_mfma_f32_16x16x32_f16(a0, bfr[s], c0, 0, 0, 0);
        c1 = __builtin_amdgcn_mfma_f32_16x16x32_f16(a1, bfr[s], c1, 0, 0, 0);
    }

    #pragma unroll
    for (int r = 0; r < 4; ++r) {
        out[(m0 + quad * 4 + r) * COUT + bcol]      = c0[r];
        out[(m0 + 16 + quad * 4 + r) * COUT + bcol] = c1[r];
    }
}

extern "C" void kernel_launch(void* const* d_in, const int* in_sizes, int n_in,
                              void* d_out, int out_size, void* d_ws, size_t ws_size,
                              hipStream_t stream) {
    const float* points        = (const float*)d_in[0];
    const float* features      = (const float*)d_in[1];
    const float* output_points = (const float*)d_in[2];
    const int*   nbr_idx       = (const int*)d_in[3];
    const int*   seg_ids       = (const int*)d_in[4];
    const float* k_points      = (const float*)d_in[5];
    const float* k_values      = (const float*)d_in[6];
    float* out = (float*)d_out;

    const size_t feat_bytes = (size_t)NPTS * FIN * sizeof(_Float16);           // 2.56 MB
    const size_t pts4_bytes = (size_t)NPTS * sizeof(float4);                   // 0.64 MB
    const size_t op4_bytes  = (size_t)MOUT * sizeof(float4);                   // 0.64 MB
    const size_t rs_bytes   = ((size_t)(MOUT + 1) * sizeof(int) + 15) & ~15ul; // 160 KB
    const size_t wt_bytes   = (size_t)KFDIM * COUT * sizeof(_Float16);         // 60 KB
    const size_t full_bytes = feat_bytes + pts4_bytes + op4_bytes + rs_bytes
                            + wt_bytes;                                        // ~4.1 MB

    if (ws_size >= full_bytes) {
        char* p = (char*)d_ws;
        _Float16* feat_i    = (_Float16*)p;  p += feat_bytes;
        float4*   points4   = (float4*)p;    p += pts4_bytes;
        float4*   op4       = (float4*)p;    p += op4_bytes;
        int*      row_start = (int*)p;       p += rs_bytes;
        _Float16* w_t       = (_Float16*)p;

        preprocess_all<<<PRE_BLKS, 256, 0, stream>>>(
            features, feat_i, points, points4, output_points, op4,
            seg_ids, row_start, k_values, w_t);
        kpconv_fused2<<<MOUT / 16, 256, 0, stream>>>(
            points4, feat_i, op4, nbr_idx, row_start, k_points, w_t, out);
    } else {
        _Float16* agg_g = (_Float16*)d_ws;   // needs 38.4 MB
        kpconv_agg_fallback<<<MOUT / 4, 256, 0, stream>>>(
            points, features, output_points, nbr_idx, seg_ids, k_points, agg_g);
        kpconv_gemm_plain<<<MOUT / 32, 256, 0, stream>>>(agg_g, k_values, out);
    }
}

// Round 14
// 105.987 us; speedup vs baseline: 1.7641x; 1.0083x over previous
//
#include <hip/hip_runtime.h>

typedef __attribute__((ext_vector_type(8))) short bf16x8;
typedef __attribute__((ext_vector_type(8))) _Float16 f16x8;
typedef __attribute__((ext_vector_type(4))) float f32x4;
typedef __attribute__((ext_vector_type(4))) _Float16 f16x4;
typedef __attribute__((ext_vector_type(2))) _Float16 f16x2;

#define NPTS   40000
#define MOUT   40000
#define EDG    500000
#define FIN    32
#define COUT   64
#define KP     15
#define KFDIM  (KP * FIN)          // 480
#define EXTENT 0.6f

// Phase-1 wave-private staging (R12-proven strides):
#define FSTRIDE 112
#define WSTRIDE 40
#define WAVE_LDS (16 * FSTRIDE + 16 * WSTRIDE)    // 2432 B/wave
// Block agg tile: 16 segments x 488 f16 (976B rows = 61*16B, conflict-free b128)
#define ASTR 488

#define FEAT_BLKS  (NPTS * FIN / 1024)            // 1250
#define PTS_BLKS   ((NPTS + 255) / 256)           // 157
#define OP_BLKS    ((MOUT + 255) / 256)           // 157
#define ROW_BLKS   ((EDG + 255) / 256)            // 1954
#define WT_BLKS    (KFDIM * COUT / 256)           // 120
#define PRE_BLKS   (FEAT_BLKS + PTS_BLKS + OP_BLKS + ROW_BLKS + WT_BLKS)

__device__ __forceinline__ short f2bf(float x) {
    union { float f; unsigned u; } v; v.f = x;
    unsigned r = (v.u + 0x7fffu + ((v.u >> 16) & 1u)) >> 16;
    return (short)r;
}

// ============================================================================
// Preprocess (ONE launch, branch by block range):
//  feat:  f32 -> f16, channel pairs interleaved: feat_i[p][2f'+h] = feat[p][f'+16h]
//  pts:   points -> float4 pad ;  op: output_points -> float4 pad
//  row:   CSR row starts via scatter (disjoint ranges, no atomics)
//  wt:    k_values f32 -> f16, transposed+interleaved: w_t[c][k*32+2f'+h] =
//         W[k*32+f'+16h][c]  (same kf order as the agg tile)
// ============================================================================
__global__ __launch_bounds__(256) void preprocess_all(
    const float* __restrict__ features, _Float16* __restrict__ feat_i,
    const float* __restrict__ pts, float4* __restrict__ p4,
    const float* __restrict__ opts, float4* __restrict__ op4,
    const int* __restrict__ seg_ids, int* __restrict__ row_start,
    const float* __restrict__ k_values, _Float16* __restrict__ w_t)
{
    const int bid = blockIdx.x;
    if (bid < FEAT_BLKS) {
        const int d0 = (bid * 256 + threadIdx.x) * 4;
        #pragma unroll
        for (int u = 0; u < 4; ++u) {
            const int d = d0 + u;
            const int p = d >> 5, q = d & 31;
            const int fp = q >> 1, h = q & 1;
            feat_i[d] = (_Float16)features[p * FIN + fp + 16 * h];
        }
    } else if (bid < FEAT_BLKS + PTS_BLKS) {
        const int i = (bid - FEAT_BLKS) * 256 + threadIdx.x;
        if (i < NPTS) {
            const float* p = pts + 3 * i;
            p4[i] = make_float4(p[0], p[1], p[2], 0.f);
        }
    } else if (bid < FEAT_BLKS + PTS_BLKS + OP_BLKS) {
        const int i = (bid - FEAT_BLKS - PTS_BLKS) * 256 + threadIdx.x;
        if (i < MOUT) {
            const float* p = opts + 3 * i;
            op4[i] = make_float4(p[0], p[1], p[2], 0.f);
        }
    } else if (bid < FEAT_BLKS + PTS_BLKS + OP_BLKS + ROW_BLKS) {
        const int e = (bid - FEAT_BLKS - PTS_BLKS - OP_BLKS) * 256 + threadIdx.x;
        if (e >= EDG) return;
        const int cur  = seg_ids[e];
        const int prev = (e == 0) ? -1 : seg_ids[e - 1];
        for (int m = prev + 1; m <= cur; ++m) row_start[m] = e;
        if (e == EDG - 1)
            for (int m = cur + 1; m <= MOUT; ++m) row_start[m] = EDG;
    } else {
        const int d = (bid - FEAT_BLKS - PTS_BLKS - OP_BLKS - ROW_BLKS) * 256
                      + threadIdx.x;                 // 0 .. 30719
        const int c = d / KFDIM, r = d % KFDIM;
        const int k = r >> 5, q = r & 31;
        const int fp = q >> 1, h = q & 1;
        w_t[d] = (_Float16)k_values[(k * FIN + fp + 16 * h) * COUT + c];
    }
}

// ============================================================================
// Fused kernel: block = 16 segments.
// Phase 1 (R12-proven edge-parallel agg, 4 segments/wave sequentially):
//   3 gather VMEM per 16-edge step + wave-private LDS transpose, 2 MFMAs.
// Barrier. Phase 2: 15x mfma 16x16x32_f16; A = ds_read_b128 from agg tile,
//   B = IN-LOOP b128 loads from w_t (L2-hot). NO B-fragment array held
//   across phase 1 (R3/R5/R10 spill lesson).
// (256,6): cap 85 VGPR — R12's agg_edge (same phase-1 structure) ran at this
// bound spill-free; phase 2 adds only ~24 transient VGPRs after the gather
// loop ends. 6 blocks/CU x 25.3KB LDS = 152KB < 160KB. Single-variable
// change vs R13 ((256,4)): +50% resident waves for the latency-bound phase 1.
// Spill tripwire: wall regression > 112 us -> revert to (256,4).
// ============================================================================
__global__ __launch_bounds__(256, 6) void kpconv_fused2(
    const float4* __restrict__ points4,
    const _Float16* __restrict__ feat_i,
    const float4* __restrict__ op4,
    const int*   __restrict__ nbr_idx,
    const int*   __restrict__ row_start,
    const float* __restrict__ k_points,
    const _Float16* __restrict__ w_t,
    float* __restrict__ out)
{
    __shared__ __align__(16) _Float16 aggT[16 * ASTR];          // 15616 B
    __shared__ __align__(16) unsigned char stage[4 * WAVE_LDS]; //  9728 B

    const int tid  = threadIdx.x;
    const int wave = tid >> 6;
    const int lane = tid & 63;
    const int quad = lane >> 4;
    const int l16  = lane & 15;
    const int esl  = lane >> 2;       // edge slot 0..15
    const int kg   = lane & 3;        // kgroup / feat-chunk index
    const int m0   = blockIdx.x * 16;

    unsigned char* fbase = stage + wave * WAVE_LDS;
    unsigned char* wbase = fbase + 16 * FSTRIDE;

    // per-lane kernel points (kgroup role)
    float kx[4], ky[4], kz[4];
    #pragma unroll
    for (int t = 0; t < 4; ++t) {
        const int k  = kg * 4 + t;
        const int kk = k < KP ? k : 0;
        kx[t] = k_points[kk * 3 + 0];
        ky[t] = k_points[kk * 3 + 1];
        kz[t] = k_points[kk * 3 + 2];
    }
    const float inv_ext = 1.f / EXTENT;

    // ---- Phase 1: 4 segments per wave ----
    for (int s4 = 0; s4 < 4; ++s4) {
        const int li = wave * 4 + s4;
        const int m  = m0 + li;
        const int e0 = row_start[m];
        const int e1 = row_start[m + 1];
        const float4 o = op4[m];

        f32x4 c_lo = {0.f, 0.f, 0.f, 0.f};
        f32x4 c_hi = {0.f, 0.f, 0.f, 0.f};

        for (int es = e0; es < e1; es += 16) {
            const int e  = es + esl;
            const int nb = nbr_idx[e < e1 ? e : e1 - 1];   // gather 1

            const uint4 fc = *(const uint4*)(feat_i + nb * FIN + kg * 8); // g2
            *(uint4*)(fbase + esl * FSTRIDE + kg * 16) = fc;

            const float4 p = points4[nb];                  // gather 3
            const float rx = p.x - o.x, ry = p.y - o.y, rz = p.z - o.z;
            const bool evalid = e < e1;
            #pragma unroll
            for (int t = 0; t < 4; ++t) {
                const float dx = rx - kx[t], dy = ry - ky[t], dz = rz - kz[t];
                float w = 1.f - sqrtf(dx * dx + dy * dy + dz * dz) * inv_ext;
                w = w > 0.f ? w : 0.f;
                if (!evalid || (kg * 4 + t) >= KP) w = 0.f;
                *(_Float16*)(wbase + (kg * 4 + t) * WSTRIDE + esl * 2) = (_Float16)w;
            }

            const f16x4 af = *(const f16x4*)(wbase + l16 * WSTRIDE + quad * 8);
            f16x2 w2[4];
            #pragma unroll
            for (int j = 0; j < 4; ++j)
                w2[j] = *(const f16x2*)(fbase + (quad * 4 + j) * FSTRIDE + l16 * 4);
            const f16x4 blo = {w2[0][0], w2[1][0], w2[2][0], w2[3][0]};
            const f16x4 bhi = {w2[0][1], w2[1][1], w2[2][1], w2[3][1]};

            c_lo = __builtin_amdgcn_mfma_f32_16x16x16f16(af, blo, c_lo, 0, 0, 0);
            c_hi = __builtin_amdgcn_mfma_f32_16x16x16f16(af, bhi, c_hi, 0, 0, 0);
        }

        // D -> agg tile row li (interleaved kf order): byte = k*64 + l16*4
        _Float16* dst = aggT + li * ASTR;
        #pragma unroll
        for (int r = 0; r < 4; ++r) {
            const int krow = quad * 4 + r;
            if (krow < KP) {
                f16x2 v = {(_Float16)c_lo[r], (_Float16)c_hi[r]};
                *(f16x2*)(dst + krow * 32 + 2 * l16) = v;
            }
        }
    }

    __syncthreads();

    // ---- Phase 2: C[16 segs x 16 cols] per wave, B in-loop from w_t ----
    const int bcol = wave * 16 + l16;
    const _Float16* wrow = w_t + (size_t)bcol * KFDIM + quad * 8;
    const _Float16* arow = aggT + l16 * ASTR + quad * 8;

    f32x4 c = {0.f, 0.f, 0.f, 0.f};
    #pragma unroll
    for (int s = 0; s < 15; ++s) {
        const f16x8 a = *(const f16x8*)(arow + 32 * s);
        const f16x8 b = *(const f16x8*)(wrow + 32 * s);
        c = __builtin_amdgcn_mfma_f32_16x16x32_f16(a, b, c, 0, 0, 0);
    }

    // C/D: col = lane&15 (-> bcol), row = quad*4 + r (= local segment)
    #pragma unroll
    for (int r = 0; r < 4; ++r)
        out[(m0 + quad * 4 + r) * COUT + bcol] = c[r];
}

// ============================================================================
// Fallback (small ws, needs 38.4 MB): binary-search K=32 agg + plain gemm.
// ============================================================================
__global__ __launch_bounds__(256, 4) void kpconv_agg_fallback(
    const float* __restrict__ points,
    const float* __restrict__ features,
    const float* __restrict__ output_points,
    const int*   __restrict__ nbr_idx,
    const int*   __restrict__ seg_ids,
    const float* __restrict__ k_points,
    _Float16* __restrict__ agg_g)
{
    __shared__ int seg_start[5];

    const int tid = threadIdx.x;
    const int m0  = blockIdx.x * 4;

    if (tid <= 4) {
        const int target = m0 + tid;
        int lo = 0, hi = EDG;
        while (lo < hi) {
            int mid = (lo + hi) >> 1;
            if (seg_ids[mid] < target) lo = mid + 1; else hi = mid;
        }
        seg_start[tid] = lo;
    }
    __syncthreads();

    const int wave = tid >> 6;
    const int lane = tid & 63;
    const int quad = lane >> 4;
    const int l16  = lane & 15;

    const int m = m0 + wave;
    const float ox = output_points[m * 3 + 0];
    const float oy = output_points[m * 3 + 1];
    const float oz = output_points[m * 3 + 2];

    const int myk = l16 < KP ? l16 : 0;
    const float kpx = k_points[myk * 3 + 0];
    const float kpy = k_points[myk * 3 + 1];
    const float kpz = k_points[myk * 3 + 2];
    const float inv_ext = 1.f / EXTENT;

    const int e0 = seg_start[wave], e1 = seg_start[wave + 1];

    f32x4 c_lo = {0.f, 0.f, 0.f, 0.f};
    f32x4 c_hi = {0.f, 0.f, 0.f, 0.f};

    for (int es = e0; es < e1; es += 32) {
        const int last = e1 - 1;
        const int ebase = es + quad * 8;

        int nb[8];
        #pragma unroll
        for (int j = 0; j < 8; ++j) {
            const int e = ebase + j;
            nb[j] = nbr_idx[e < e1 ? e : last];
        }

        bf16x8 afrag, blo, bhi;
        #pragma unroll
        for (int j = 0; j < 8; ++j) {
            const float* pp = points + nb[j] * 3;
            const float rx = pp[0] - ox;
            const float ry = pp[1] - oy;
            const float rz = pp[2] - oz;
            const float dx = rx - kpx, dy = ry - kpy, dz = rz - kpz;
            const float d2 = dx * dx + dy * dy + dz * dz;
            float w = 1.f - sqrtf(d2) * inv_ext;
            w = w > 0.f ? w : 0.f;
            if (l16 >= KP || ebase + j >= e1) w = 0.f;
            afrag[j] = f2bf(w);
        }

        #pragma unroll
        for (int j = 0; j < 8; ++j) {
            const float* fp = features + nb[j] * FIN + l16;
            blo[j] = f2bf(fp[0]);
            bhi[j] = f2bf(fp[16]);
        }

        c_lo = __builtin_amdgcn_mfma_f32_16x16x32_bf16(afrag, blo, c_lo, 0, 0, 0);
        c_hi = __builtin_amdgcn_mfma_f32_16x16x32_bf16(afrag, bhi, c_hi, 0, 0, 0);
    }

    _Float16* dst = agg_g + (size_t)m * KFDIM;
    #pragma unroll
    for (int r = 0; r < 4; ++r) {
        const int krow = quad * 4 + r;
        if (krow < KP) {
            dst[krow * FIN + l16]      = (_Float16)c_lo[r];
            dst[krow * FIN + 16 + l16] = (_Float16)c_hi[r];
        }
    }
}

__global__ __launch_bounds__(256, 4) void kpconv_gemm_plain(
    const _Float16* __restrict__ agg_g,
    const float* __restrict__ k_values,
    float* __restrict__ out)
{
    const int tid  = threadIdx.x;
    const int wave = tid >> 6;
    const int lane = tid & 63;
    const int quad = lane >> 4;
    const int l16  = lane & 15;
    const int m0   = blockIdx.x * 32;
    const int bcol = wave * 16 + l16;

    f16x8 bfr[15];
    #pragma unroll
    for (int s = 0; s < 15; ++s) {
        #pragma unroll
        for (int j = 0; j < 8; ++j)
            bfr[s][j] = (_Float16)k_values[(32 * s + quad * 8 + j) * COUT + bcol];
    }

    const _Float16* arow0 = agg_g + (size_t)(m0 + l16) * KFDIM + quad * 8;
    const _Float16* arow1 = arow0 + 16 * KFDIM;

    f32x4 c0 = {0.f, 0.f, 0.f, 0.f};
    f32x4 c1 = {0.f, 0.f, 0.f, 0.f};
    #pragma unroll
    for (int s = 0; s < 15; ++s) {
        const f16x8 a0 = *(const f16x8*)(arow0 + 32 * s);
        const f16x8 a1 = *(const f16x8*)(arow1 + 32 * s);
        c0 = __builtin_amdgcn_mfma_f32_16x16x32_f16(a0, bfr[s], c0, 0, 0, 0);
        c1 = __builtin_amdgcn_mfma_f32_16x16x32_f16(a1, bfr[s], c1, 0, 0, 0);
    }

    #pragma unroll
    for (int r = 0; r < 4; ++r) {
        out[(m0 + quad * 4 + r) * COUT + bcol]      = c0[r];
        out[(m0 + 16 + quad * 4 + r) * COUT + bcol] = c1[r];
    }
}

extern "C" void kernel_launch(void* const* d_in, const int* in_sizes, int n_in,
                              void* d_out, int out_size, void* d_ws, size_t ws_size,
                              hipStream_t stream) {
    const float* points        = (const float*)d_in[0];
    const float* features      = (const float*)d_in[1];
    const float* output_points = (const float*)d_in[2];
    const int*   nbr_idx       = (const int*)d_in[3];
    const int*   seg_ids       = (const int*)d_in[4];
    const float* k_points      = (const float*)d_in[5];
    const float* k_values      = (const float*)d_in[6];
    float* out = (float*)d_out;

    const size_t feat_bytes = (size_t)NPTS * FIN * sizeof(_Float16);           // 2.56 MB
    const size_t pts4_bytes = (size_t)NPTS * sizeof(float4);                   // 0.64 MB
    const size_t op4_bytes  = (size_t)MOUT * sizeof(float4);                   // 0.64 MB
    const size_t rs_bytes   = ((size_t)(MOUT + 1) * sizeof(int) + 15) & ~15ul; // 160 KB
    const size_t wt_bytes   = (size_t)KFDIM * COUT * sizeof(_Float16);         // 60 KB
    const size_t full_bytes = feat_bytes + pts4_bytes + op4_bytes + rs_bytes
                            + wt_bytes;                                        // ~4.1 MB

    if (ws_size >= full_bytes) {
        char* p = (char*)d_ws;
        _Float16* feat_i    = (_Float16*)p;  p += feat_bytes;
        float4*   points4   = (float4*)p;    p += pts4_bytes;
        float4*   op4       = (float4*)p;    p += op4_bytes;
        int*      row_start = (int*)p;       p += rs_bytes;
        _Float16* w_t       = (_Float16*)p;

        preprocess_all<<<PRE_BLKS, 256, 0, stream>>>(
            features, feat_i, points, points4, output_points, op4,
            seg_ids, row_start, k_values, w_t);
        kpconv_fused2<<<MOUT / 16, 256, 0, stream>>>(
            points4, feat_i, op4, nbr_idx, row_start, k_points, w_t, out);
    } else {
        _Float16* agg_g = (_Float16*)d_ws;   // needs 38.4 MB
        kpconv_agg_fallback<<<MOUT / 4, 256, 0, stream>>>(
            points, features, output_points, nbr_idx, seg_ids, k_points, agg_g);
        kpconv_gemm_plain<<<MOUT / 32, 256, 0, stream>>>(agg_g, k_values, out);
    }
}